// Round 14
// baseline (61.262 us; speedup 1.0000x reference)
//
#include <hip/hip_runtime.h>

// Problem constants (fixed inputs: ref_index=[0,1,2], current_ind=16)
// -> nsearch=1, dirates=[2], nref=3
// feats_r: (3,1,64,64,64) f32, feats_t: (1,64,64,64) f32,
// quantized_r: (3,1,1,256,256) i32
// out: (1,32,64,64) f32 then grid: (3,64,64,2) f32

#define NPIX 4096   // 64*64

// 16-channel partial dot (this lane's quarter of the 64-ch dot).
__device__ __forceinline__ float pdot16(float4 t0, float4 t1, float4 t2,
                                        float4 t3, float4 a, float4 b,
                                        float4 c, float4 d) {
  float s0 = t0.x * a.x, s1 = t0.y * a.y, s2 = t0.z * a.z, s3 = t0.w * a.w;
  s0 = fmaf(t1.x, b.x, s0); s1 = fmaf(t1.y, b.y, s1);
  s2 = fmaf(t1.z, b.z, s2); s3 = fmaf(t1.w, b.w, s3);
  s0 = fmaf(t2.x, c.x, s0); s1 = fmaf(t2.y, c.y, s1);
  s2 = fmaf(t2.z, c.z, s2); s3 = fmaf(t2.w, c.w, s3);
  s0 = fmaf(t3.x, d.x, s0); s1 = fmaf(t3.y, d.y, s1);
  s2 = fmaf(t3.z, d.z, s2); s3 = fmaf(t3.w, d.w, s3);
  return (s0 + s1) + (s2 + s3);
}

// 4-lane transpose-reduce: p0..p3 = this lane's 16-ch partials for pixels
// 0..3; result: lane tx holds the full 64-ch dot of pixel tx. 3 shfl,
// 2 dependent levels.
__device__ __forceinline__ float xpose_reduce4(float p0, float p1, float p2,
                                               float p3, int tx) {
  bool o1 = tx & 1, o2 = tx & 2;
  float x01 = __shfl_xor(o1 ? p0 : p1, 1);
  float x23 = __shfl_xor(o1 ? p2 : p3, 1);
  float sA = (o1 ? p1 : p0) + x01;
  float sB = (o1 ? p3 : p2) + x23;
  float z = __shfl_xor(o2 ? sA : sB, 2);
  return o2 ? (sB + z) : (sA + z);
}

// All-lanes sum over a 4-lane group (2 shfl).
__device__ __forceinline__ float red4(float v) {
  v += __shfl_xor(v, 1);
  v += __shfl_xor(v, 2);
  return v;
}

__device__ __forceinline__ float wredmax(float v) {
#pragma unroll
  for (int o = 32; o; o >>= 1) v = fmaxf(v, __shfl_down(v, o));
  return __shfl(v, 0);
}
__device__ __forceinline__ float wredsum(float v) {
#pragma unroll
  for (int o = 32; o; o >>= 1) v += __shfl_down(v, o);
  return __shfl(v, 0);
}

// ---------------------------------------------------------------------------
// K0: transpose [c][pix] -> [pix][c] (float4 both sides via LDS tile), pack
// the (::4,::4) label planes into dense uchar[3][4096], and zero `out`.
__global__ __launch_bounds__(256) void k_transpose(
    const float* __restrict__ ft, const float* __restrict__ fr,
    const int* __restrict__ q, float* __restrict__ tT, float* __restrict__ rT,
    unsigned char* __restrict__ lblp, float* __restrict__ out) {
  __shared__ float tile[64][65];
  int img = blockIdx.y;
  int pixBase = blockIdx.x * 64;
  const float* src = (img == 0) ? ft : fr + (img - 1) * (64 * NPIX);
  float* dst = (img == 0) ? tT : rT + (img - 1) * (64 * NPIX);
  int tid = threadIdx.x;
#pragma unroll
  for (int it = 0; it < 4; ++it) {
    int idx = it * 256 + tid;
    int c = idx >> 4;
    int p4 = (idx & 15) << 2;
    float4 v = *(const float4*)&src[c * NPIX + pixBase + p4];
    tile[p4 + 0][c] = v.x;
    tile[p4 + 1][c] = v.y;
    tile[p4 + 2][c] = v.z;
    tile[p4 + 3][c] = v.w;
  }
  __syncthreads();
#pragma unroll
  for (int it = 0; it < 4; ++it) {
    int idx = it * 256 + tid;
    int p = idx >> 4;
    int c4 = (idx & 15) << 2;
    float4 v = make_float4(tile[p][c4], tile[p][c4 + 1], tile[p][c4 + 2],
                           tile[p][c4 + 3]);
    *(float4*)&dst[(pixBase + p) * 64 + c4] = v;
  }
  if (img >= 1 && tid < 64) {
    int pix = pixBase + tid;
    lblp[(img - 1) * 4096 + pix] = (unsigned char)
        q[(img - 1) * 65536 + (pix >> 6) * 1024 + (pix & 63) * 4];
  }
  // zero out[131072]: 65536 threads x 2
  int gi = (blockIdx.y * 64 + blockIdx.x) * 256 + tid;
  out[gi] = 0.f;
  out[gi + 65536] = 0.f;
}

// ---------------------------------------------------------------------------
// K1: 256 threads (4 waves), 4 pixels per block; wave w owns pixel w.
// blockIdx.z: 0 = offsets+ref0 (stride-2 pixels), 1/2 = plain ref k
// (consecutive pixels). 4-lane channel groups (16 ch/lane) in all dot
// phases. All paths atomicAdd into pre-zeroed out.
__global__ __launch_bounds__(256, 4) void k_fused(
    const float* __restrict__ tT, const float* __restrict__ rT,
    const unsigned char* __restrict__ lblp, float* __restrict__ out,
    float* __restrict__ grid) {
  int xg = blockIdx.x, y = blockIdx.y, z = blockIdx.z;
  int tid = threadIdx.x;
  int g4 = tid >> 2, tx = tid & 3;    // 64 groups of 4 lanes
  int w = tid >> 6, lane = tid & 63;  // 4 waves; wave w -> pixel w

  __shared__ float cc1[4 * 636];   // z=0: 625-tap maps; z>0: cc2[4][169]
  __shared__ float D[4][196];      // z=0: deformed 14x14 dot grids
  __shared__ float P0[4][169];     // z=0: normalized ref0 corr
  __shared__ float bins[4][33];    // per-pixel histograms

  if (tid < 132) ((float*)bins)[tid] = 0.f;

  int opix;  // this block's pixel for out-write lane mapping (set per path)

  if (z == 0) {
    int x0 = (xg >> 1) * 8 + (xg & 1);  // pixels x0 + {0,2,4,6}
    opix = x0;
    // t fragments: lane tx holds channels [16tx,16tx+16) of 4 stride-2 px.
    const float4* tb = (const float4*)&tT[((y << 6) + x0) << 6];
    float4 t00 = tb[0 * 32 + 4 * tx + 0], t01 = tb[0 * 32 + 4 * tx + 1],
           t02 = tb[0 * 32 + 4 * tx + 2], t03 = tb[0 * 32 + 4 * tx + 3];
    float4 t10 = tb[1 * 32 + 4 * tx + 0], t11 = tb[1 * 32 + 4 * tx + 1],
           t12 = tb[1 * 32 + 4 * tx + 2], t13 = tb[1 * 32 + 4 * tx + 3];
    float4 t20 = tb[2 * 32 + 4 * tx + 0], t21 = tb[2 * 32 + 4 * tx + 1],
           t22 = tb[2 * 32 + 4 * tx + 2], t23 = tb[2 * 32 + 4 * tx + 3];
    float4 t30 = tb[3 * 32 + 4 * tx + 0], t31 = tb[3 * 32 + 4 * tx + 1],
           t32 = tb[3 * 32 + 4 * tx + 2], t33 = tb[3 * 32 + 4 * tx + 3];

    // ---- ph1: 25x28 union dilated dots, 64 groups x 11 rounds.
    {
      int row = g4 / 28;
      int col = g4 - row * 28;
#pragma unroll 2
      for (int r = 0; r < 11; ++r) {
        bool rowok = row < 25;
        int rx = x0 - 24 + 2 * col;
        int ry = y + 2 * row - 24;
        bool ok = rowok & ((unsigned)rx < 64u) & ((unsigned)ry < 64u);
        const float4* rp = (const float4*)
            &rT[min(max(ry, 0), 63) * 4096 + min(max(rx, 0), 63) * 64 +
                tx * 16];
        float4 ra = rp[0], rb = rp[1], rc = rp[2], rd = rp[3];
        float p0 = pdot16(t00, t01, t02, t03, ra, rb, rc, rd);
        float p1 = pdot16(t10, t11, t12, t13, ra, rb, rc, rd);
        float p2 = pdot16(t20, t21, t22, t23, ra, rb, rc, rd);
        float p3 = pdot16(t30, t31, t32, t33, ra, rb, rc, rd);
        float v = xpose_reduce4(p0, p1, p2, p3, tx);
        v = ok ? v : 0.f;
        int ox = col - tx;  // lane tx owns pixel tx
        if (rowok && (unsigned)ox < 25u) cc1[tx * 636 + row * 25 + ox] = v;
        // advance tap by 64: +2 rows +8 cols (64 = 2*28 + 8)
        row += 2;
        col += 8;
        if (col >= 28) { col -= 28; ++row; }
      }
    }
    __syncthreads();  // cc1 complete (covers bins init too)

    // ---- ph2: offset softmax-expectation (wave w, pixel w; in regs)
    float offx, offy;
    {
      float vv[10];
      float m = -3e38f;
#pragma unroll
      for (int it = 0; it < 10; ++it) {
        unsigned o = lane + (it << 6);
        float v = (o < 625u) ? cc1[w * 636 + o] : -3e38f;
        vv[it] = v;
        m = fmaxf(m, v);
      }
      m = wredmax(m);
      float s = 0.f, sx = 0.f, sy = 0.f;
#pragma unroll
      for (int it = 0; it < 10; ++it) {
        unsigned o = lane + (it << 6);
        unsigned oy = o / 25u, ox = o - oy * 25u;
        float e = __expf(vv[it] - m);
        s += e;
        sx += e * (float)((int)ox - 12);
        sy += e * (float)((int)oy - 12);
      }
      s = wredsum(s);
      sx = wredsum(sx);
      sy = wredsum(sy);
      offx = 2.f * sx / s;
      offy = 2.f * sy / s;
    }

    float fy = floorf(offy), fx = floorf(offx);
    float wy = offy - fy, wx = offx - fx;
    float w00 = (1.f - wy) * (1.f - wx), w01 = (1.f - wy) * wx;
    float w10 = wy * (1.f - wx), w11 = wy * wx;
    int iy0 = y + (int)fy - 6;
    int ix0 = x0 + 2 * w + (int)fx - 6;

    // ---- ph3: deformed 14x14 dot grid for own pixel (wave-local,
    // 16 4-lane groups, round r = grid row, b = lane>>2 = grid col)
    {
      const float4* Tp = (const float4*)&tT[((y << 6) + x0 + 2 * w) << 6];
      float4 T0 = Tp[4 * tx], T1 = Tp[4 * tx + 1], T2 = Tp[4 * tx + 2],
             T3 = Tp[4 * tx + 3];
      int b = lane >> 2;
#pragma unroll 2
      for (int r = 0; r < 14; ++r) {
        int ry = iy0 + r, rx = ix0 + b;
        bool ok = (b < 14) & ((unsigned)ry < 64u) & ((unsigned)rx < 64u);
        const float4* rp = (const float4*)
            &rT[(min(max(ry, 0), 63) * 64 + min(max(rx, 0), 63)) * 64 +
                tx * 16];
        float4 ra = rp[0], rb = rp[1], rc = rp[2], rd = rp[3];
        float v = red4(pdot16(T0, T1, T2, T3, ra, rb, rc, rd));
        if (tx == 0 && b < 14) D[w][r * 14 + b] = ok ? v : 0.f;
      }
    }

    // ---- ph4: ref0 bilinear-combine gaussian softmax (wave-local)
    {
      int px = x0 + 2 * w, pix = (y << 6) + px;
      float sc[3];
      float m = -3e38f;
#pragma unroll
      for (int it = 0; it < 3; ++it) {
        unsigned o = lane + (it << 6);
        float scv = -3e38f;
        if (o < 169u) {
          unsigned i = o / 13u, j = o - i * 13u;
          float v = w00 * D[w][i * 14 + j] + w01 * D[w][i * 14 + j + 1] +
                    w10 * D[w][(i + 1) * 14 + j] +
                    w11 * D[w][(i + 1) * 14 + j + 1];
          float di = (float)(((int)i - 6) * ((int)i - 6) +
                             ((int)j - 6) * ((int)j - 6));
          scv = 50.f * __expf(-0.5f * di) * v;
        }
        sc[it] = scv;
        m = fmaxf(m, scv);
      }
      m = wredmax(m);
      float ee[3];
      float s = 0.f, gx = 0.f, gy = 0.f;
#pragma unroll
      for (int it = 0; it < 3; ++it) {
        unsigned o = lane + (it << 6);
        unsigned i = o / 13u, j = o - i * 13u;
        float e = __expf(sc[it] - m);
        ee[it] = e;
        int yy = y + (int)i - 6, xx = px + (int)j - 6;
        bool inb = (o < 169u) && (unsigned)yy < 64u && (unsigned)xx < 64u;
        s += e;
        gx += e * (inb ? (-1.f + (2.f / 63.f) * (float)xx) : 0.f);
        gy += e * (inb ? (-1.f + (2.f / 63.f) * (float)yy) : 0.f);
      }
      s = wredsum(s);
      gx = wredsum(gx);
      gy = wredsum(gy);
      float invS = 1.f / s;
#pragma unroll
      for (int it = 0; it < 3; ++it) {
        unsigned o = lane + (it << 6);
        if (o < 169u) P0[w][o] = ee[it] * invS;
      }
      if (lane == 0) {
        grid[pix * 2 + 0] = gx * invS;
        grid[pix * 2 + 1] = gy * invS;
      }
    }

    // ---- ph5: ref0 inverse-bilinear histogram (wave-local)
    {
#pragma unroll
      for (int it = 0; it < 4; ++it) {
        int idx = lane + (it << 6);  // 14x16-padded
        int a = idx >> 4, b = idx & 15;
        if (a < 14 && b < 14) {
          int ry = iy0 + a, rx = ix0 + b;
          if ((unsigned)ry < 64u && (unsigned)rx < 64u) {
            float wgt = 0.f;
            const float* crp = P0[w];
            if (a < 13) {
              if (b < 13) wgt = fmaf(w00, crp[a * 13 + b], wgt);
              if (b > 0) wgt = fmaf(w01, crp[a * 13 + b - 1], wgt);
            }
            if (a > 0) {
              if (b < 13) wgt = fmaf(w10, crp[(a - 1) * 13 + b], wgt);
              if (b > 0) wgt = fmaf(w11, crp[(a - 1) * 13 + b - 1], wgt);
            }
            if (wgt != 0.f) atomicAdd(&bins[w][lblp[ry * 64 + rx]], wgt);
          }
        }
      }
    }
    __syncthreads();  // bins settled before out write
  } else {
    // ---------------- z = k in {1,2}: plain ref, 4 consecutive pixels -----
    int k = z;
    int x0c = xg * 4;
    opix = -x0c - 1;  // flag consecutive mapping
    const float* rb0 = rT + (k << 18);
    float (*cc2)[169] = (float(*)[169])cc1;
    const float4* tb = (const float4*)&tT[((y << 6) + x0c) << 6];
    float4 t00 = tb[0 * 16 + 4 * tx + 0], t01 = tb[0 * 16 + 4 * tx + 1],
           t02 = tb[0 * 16 + 4 * tx + 2], t03 = tb[0 * 16 + 4 * tx + 3];
    float4 t10 = tb[1 * 16 + 4 * tx + 0], t11 = tb[1 * 16 + 4 * tx + 1],
           t12 = tb[1 * 16 + 4 * tx + 2], t13 = tb[1 * 16 + 4 * tx + 3];
    float4 t20 = tb[2 * 16 + 4 * tx + 0], t21 = tb[2 * 16 + 4 * tx + 1],
           t22 = tb[2 * 16 + 4 * tx + 2], t23 = tb[2 * 16 + 4 * tx + 3];
    float4 t30 = tb[3 * 16 + 4 * tx + 0], t31 = tb[3 * 16 + 4 * tx + 1],
           t32 = tb[3 * 16 + 4 * tx + 2], t33 = tb[3 * 16 + 4 * tx + 3];

    // ---- ph6: 13x16 union dots -> cc2[px][i*13+j], 4 rounds of 64 groups
    {
#pragma unroll 2
      for (int r = 0; r < 4; ++r) {
        int idx = g4 + (r << 6);  // 0..255, active < 208 (i < 13)
        int i = idx >> 4, u = idx & 15;
        int ry = y + i - 6, rx = x0c - 6 + u;
        bool ok = (i < 13) & ((unsigned)ry < 64u) & ((unsigned)rx < 64u);
        const float4* rp = (const float4*)
            &rb0[min(max(ry, 0), 63) * 4096 + min(max(rx, 0), 63) * 64 +
                 tx * 16];
        float4 ra = rp[0], rb = rp[1], rc = rp[2], rd = rp[3];
        float p0 = pdot16(t00, t01, t02, t03, ra, rb, rc, rd);
        float p1 = pdot16(t10, t11, t12, t13, ra, rb, rc, rd);
        float p2 = pdot16(t20, t21, t22, t23, ra, rb, rc, rd);
        float p3 = pdot16(t30, t31, t32, t33, ra, rb, rc, rd);
        float v = xpose_reduce4(p0, p1, p2, p3, tx);
        v = ok ? v : 0.f;
        int j = u - tx;  // lane tx owns pixel tx
        if ((i < 13) && ((unsigned)j < 13u)) cc2[tx][i * 13 + j] = v;
      }
    }
    __syncthreads();  // cc2 complete (covers bins init too)

    // ---- ph7: gaussian softmax + grid + histogram (wave w, pixel w)
    {
      int px = x0c + w, pix = (y << 6) + px;
      float sc[3];
      float m = -3e38f;
#pragma unroll
      for (int it = 0; it < 3; ++it) {
        unsigned o = lane + (it << 6);
        float scv = -3e38f;
        if (o < 169u) {
          unsigned i = o / 13u, j = o - i * 13u;
          float di = (float)(((int)i - 6) * ((int)i - 6) +
                             ((int)j - 6) * ((int)j - 6));
          scv = 50.f * __expf(-0.5f * di) * cc2[w][o];
        }
        sc[it] = scv;
        m = fmaxf(m, scv);
      }
      m = wredmax(m);
      float ee[3];
      float s = 0.f, gx = 0.f, gy = 0.f;
#pragma unroll
      for (int it = 0; it < 3; ++it) {
        unsigned o = lane + (it << 6);
        unsigned i = o / 13u, j = o - i * 13u;
        float e = __expf(sc[it] - m);
        ee[it] = e;
        int yy = y + (int)i - 6, xx = px + (int)j - 6;
        bool inb = (o < 169u) && (unsigned)yy < 64u && (unsigned)xx < 64u;
        s += e;
        gx += e * (inb ? (-1.f + (2.f / 63.f) * (float)xx) : 0.f);
        gy += e * (inb ? (-1.f + (2.f / 63.f) * (float)yy) : 0.f);
      }
      s = wredsum(s);
      gx = wredsum(gx);
      gy = wredsum(gy);
      float invS = 1.f / s;
#pragma unroll
      for (int it = 0; it < 3; ++it) {
        unsigned o = lane + (it << 6);
        if (o < 169u) {
          unsigned i = o / 13u, j = o - i * 13u;
          int yy = y + (int)i - 6, xx = px + (int)j - 6;
          if ((unsigned)yy < 64u && (unsigned)xx < 64u)
            atomicAdd(&bins[w][lblp[(k << 12) + yy * 64 + xx]],
                      ee[it] * invS);
        }
      }
      if (lane == 0) {
        grid[(k * NPIX + pix) * 2 + 0] = gx * invS;
        grid[(k * NPIX + pix) * 2 + 1] = gy * invS;
      }
    }
    __syncthreads();  // bins settled before out write
  }

  // ---- out accumulate: 32 ch x 4 px (out pre-zeroed; 3 adds/elem total)
  if (tid < 128) {
    int pp = tid & 3, c = tid >> 2;
    int px = (opix >= 0) ? (opix + 2 * pp) : (-opix - 1 + pp);
    atomicAdd(&out[c * NPIX + (y << 6) + px], bins[pp][c]);
  }
}

// ---------------------------------------------------------------------------
extern "C" void kernel_launch(void* const* d_in, const int* in_sizes, int n_in,
                              void* d_out, int out_size, void* d_ws,
                              size_t ws_size, hipStream_t stream) {
  const float* fr = (const float*)d_in[0];  // feats_r (3,1,64,64,64)
  const float* ft = (const float*)d_in[1];  // feats_t (1,64,64,64)
  const int* q = (const int*)d_in[2];       // quantized_r (3,1,1,256,256)
  float* out = (float*)d_out;               // 131072 + 24576 floats
  float* grid = out + 32 * NPIX;

  float* ws = (float*)d_ws;
  float* tT = ws;                                        // 4096*64
  float* rT = ws + 262144;                               // 3*4096*64
  unsigned char* lblp = (unsigned char*)(ws + 1048576);  // 3*4096 uchar

  k_transpose<<<dim3(64, 4), 256, 0, stream>>>(ft, fr, q, tT, rT, lblp, out);
  k_fused<<<dim3(16, 64, 3), 256, 0, stream>>>(tT, rT, lblp, out, grid);
}

// Round 15
// 49.454 us; speedup vs baseline: 1.2388x; 1.2388x over previous
//
#include <hip/hip_runtime.h>

// Problem constants (fixed inputs: ref_index=[0,1,2], current_ind=16)
// -> nsearch=1, dirates=[2], nref=3
// feats_r: (3,1,64,64,64) f32, feats_t: (1,64,64,64) f32,
// quantized_r: (3,1,1,256,256) i32
// out: (1,32,64,64) f32 then grid: (3,64,64,2) f32

#define NPIX 4096   // 64*64

// 8-channel partial dot (this lane's eighth of the 64-ch dot).
__device__ __forceinline__ float pdot8(float4 t0, float4 t1, float4 a,
                                       float4 b) {
  float s0 = t0.x * a.x, s1 = t0.y * a.y, s2 = t0.z * a.z, s3 = t0.w * a.w;
  s0 = fmaf(t1.x, b.x, s0);
  s1 = fmaf(t1.y, b.y, s1);
  s2 = fmaf(t1.z, b.z, s2);
  s3 = fmaf(t1.w, b.w, s3);
  return (s0 + s1) + (s2 + s3);
}

// 8-lane-group reduce of 4 per-pixel partials: fold upper half, then 4-lane
// transpose-reduce. Lane tx: (tx&3) holds pixel (tx&3)'s full 64-ch dot.
__device__ __forceinline__ float red8_4(float p0, float p1, float p2,
                                        float p3, int tx) {
  p0 += __shfl_xor(p0, 4);
  p1 += __shfl_xor(p1, 4);
  p2 += __shfl_xor(p2, 4);
  p3 += __shfl_xor(p3, 4);
  int t2 = tx & 3;
  bool o1 = t2 & 1, o2 = t2 & 2;
  float x01 = __shfl_xor(o1 ? p0 : p1, 1);
  float x23 = __shfl_xor(o1 ? p2 : p3, 1);
  float sA = (o1 ? p1 : p0) + x01;
  float sB = (o1 ? p3 : p2) + x23;
  float z = __shfl_xor(o2 ? sA : sB, 2);
  return o2 ? (sB + z) : (sA + z);
}

// All-lanes sum over an 8-lane group.
__device__ __forceinline__ float red8(float v) {
  v += __shfl_xor(v, 1);
  v += __shfl_xor(v, 2);
  v += __shfl_xor(v, 4);
  return v;
}

__device__ __forceinline__ float wredmax(float v) {
#pragma unroll
  for (int o = 32; o; o >>= 1) v = fmaxf(v, __shfl_down(v, o));
  return __shfl(v, 0);
}
__device__ __forceinline__ float wredsum(float v) {
#pragma unroll
  for (int o = 32; o; o >>= 1) v += __shfl_down(v, o);
  return __shfl(v, 0);
}

// ---------------------------------------------------------------------------
// K0: transpose [c][pix] -> [pix][c] (float4 both sides via LDS tile), pack
// the (::4,::4) label planes into dense uchar[3][4096], and zero `out`.
__global__ __launch_bounds__(256) void k_transpose(
    const float* __restrict__ ft, const float* __restrict__ fr,
    const int* __restrict__ q, float* __restrict__ tT, float* __restrict__ rT,
    unsigned char* __restrict__ lblp, float* __restrict__ out) {
  __shared__ float tile[64][65];
  int img = blockIdx.y;
  int pixBase = blockIdx.x * 64;
  const float* src = (img == 0) ? ft : fr + (img - 1) * (64 * NPIX);
  float* dst = (img == 0) ? tT : rT + (img - 1) * (64 * NPIX);
  int tid = threadIdx.x;
#pragma unroll
  for (int it = 0; it < 4; ++it) {
    int idx = it * 256 + tid;
    int c = idx >> 4;
    int p4 = (idx & 15) << 2;
    float4 v = *(const float4*)&src[c * NPIX + pixBase + p4];
    tile[p4 + 0][c] = v.x;
    tile[p4 + 1][c] = v.y;
    tile[p4 + 2][c] = v.z;
    tile[p4 + 3][c] = v.w;
  }
  __syncthreads();
#pragma unroll
  for (int it = 0; it < 4; ++it) {
    int idx = it * 256 + tid;
    int p = idx >> 4;
    int c4 = (idx & 15) << 2;
    float4 v = make_float4(tile[p][c4], tile[p][c4 + 1], tile[p][c4 + 2],
                           tile[p][c4 + 3]);
    *(float4*)&dst[(pixBase + p) * 64 + c4] = v;
  }
  if (img >= 1 && tid < 64) {
    int pix = pixBase + tid;
    lblp[(img - 1) * 4096 + pix] = (unsigned char)
        q[(img - 1) * 65536 + (pix >> 6) * 1024 + (pix & 63) * 4];
  }
  // zero out[131072]: 65536 threads x 2
  int gi = (blockIdx.y * 64 + blockIdx.x) * 256 + tid;
  out[gi] = 0.f;
  out[gi + 65536] = 0.f;
}

// ---------------------------------------------------------------------------
// K1: 256 threads (4 waves), 4 pixels per block; wave w owns pixel w.
// blockIdx.z: 0 = offsets+ref0 (stride-2 pixels), 1/2 = plain ref k
// (consecutive pixels). All paths atomicAdd into pre-zeroed out.
__global__ __launch_bounds__(256, 6) void k_fused(
    const float* __restrict__ tT, const float* __restrict__ rT,
    const unsigned char* __restrict__ lblp, float* __restrict__ out,
    float* __restrict__ grid) {
  int xg = blockIdx.x, y = blockIdx.y, z = blockIdx.z;
  int tid = threadIdx.x;
  int g = tid >> 3, tx = tid & 7;     // 32 groups of 8 lanes
  int w = tid >> 6, lane = tid & 63;  // 4 waves; wave w -> pixel w

  __shared__ float cc1[4 * 636];   // z=0: 625-tap maps; z>0: cc2[4][169]
  __shared__ float D[4][196];      // z=0: deformed 14x14 dot grids
  __shared__ float P0[4][169];     // z=0: normalized ref0 corr
  __shared__ float bins[4][33];    // per-pixel histograms

  if (tid < 132) ((float*)bins)[tid] = 0.f;

  int opix;  // this block's pixel for out-write lane mapping (set per path)

  if (z == 0) {
    int x0 = (xg >> 1) * 8 + (xg & 1);  // pixels x0 + {0,2,4,6}
    opix = x0;
    // t fragments: lane tx holds channels [8tx,8tx+8) of 4 stride-2 pixels.
    const float4* tb = (const float4*)&tT[((y << 6) + x0) << 6];
    float4 t0a = tb[0 * 32 + 2 * tx], t0b = tb[0 * 32 + 2 * tx + 1];
    float4 t1a = tb[1 * 32 + 2 * tx], t1b = tb[1 * 32 + 2 * tx + 1];
    float4 t2a = tb[2 * 32 + 2 * tx], t2b = tb[2 * 32 + 2 * tx + 1];
    float4 t3a = tb[3 * 32 + 2 * tx], t3b = tb[3 * 32 + 2 * tx + 1];

    // ---- ph1: 25x28 union dilated dots; round r = row oy, group g = col u.
    __builtin_amdgcn_s_setprio(1);
    {
      int u = g;
      int rx = x0 - 24 + 2 * u;
      bool cok = (unsigned)rx < 64u;
      int colB = min(max(rx, 0), 63) * 64 + tx * 8;
      int ox = u - (tx & 3);
      bool sok = (tx < 4) & ((unsigned)ox < 25u);
#pragma unroll 4
      for (int r = 0; r < 25; ++r) {
        int ry = y + 2 * r - 24;
        bool ok = cok & ((unsigned)ry < 64u);
        const float4* rp =
            (const float4*)&rT[min(max(ry, 0), 63) * 4096 + colB];
        float4 ra = rp[0], rb = rp[1];
        float v = red8_4(pdot8(t0a, t0b, ra, rb), pdot8(t1a, t1b, ra, rb),
                         pdot8(t2a, t2b, ra, rb), pdot8(t3a, t3b, ra, rb),
                         tx);
        v = ok ? v : 0.f;
        if (sok) cc1[(tx & 3) * 636 + r * 25 + ox] = v;
      }
    }
    __builtin_amdgcn_s_setprio(0);
    __syncthreads();  // cc1 complete (covers bins init too)

    // ---- ph2: offset softmax-expectation (wave w, pixel w; in regs)
    float offx, offy;
    {
      float vv[10];
      float m = -3e38f;
#pragma unroll
      for (int it = 0; it < 10; ++it) {
        unsigned o = lane + (it << 6);
        float v = (o < 625u) ? cc1[w * 636 + o] : -3e38f;
        vv[it] = v;
        m = fmaxf(m, v);
      }
      m = wredmax(m);
      float s = 0.f, sx = 0.f, sy = 0.f;
#pragma unroll
      for (int it = 0; it < 10; ++it) {
        unsigned o = lane + (it << 6);
        unsigned oy = o / 25u, ox = o - oy * 25u;
        float e = __expf(vv[it] - m);
        s += e;
        sx += e * (float)((int)ox - 12);
        sy += e * (float)((int)oy - 12);
      }
      s = wredsum(s);
      sx = wredsum(sx);
      sy = wredsum(sy);
      offx = 2.f * sx / s;
      offy = 2.f * sy / s;
    }

    float fy = floorf(offy), fx = floorf(offx);
    float wy = offy - fy, wx = offx - fx;
    float w00 = (1.f - wy) * (1.f - wx), w01 = (1.f - wy) * wx;
    float w10 = wy * (1.f - wx), w11 = wy * wx;
    int iy0 = y + (int)fy - 6;
    int ix0 = x0 + 2 * w + (int)fx - 6;

    // ---- ph3: deformed 14x14 dot grid for own pixel (wave-local)
    __builtin_amdgcn_s_setprio(1);
    {
      const float4* Tp = (const float4*)&tT[((y << 6) + x0 + 2 * w) << 6];
      float4 T0 = Tp[2 * tx], T1 = Tp[2 * tx + 1];
      int g3 = lane >> 3;
#pragma unroll 4
      for (int r = 0; r < 28; ++r) {
        int idx = g3 + (r << 3);  // 0..223 over 14x16-padded grid
        int a = idx >> 4, b = idx & 15;
        int ry = iy0 + a, rx = ix0 + b;
        bool ok = (b < 14) & ((unsigned)ry < 64u) & ((unsigned)rx < 64u);
        const float4* rp = (const float4*)
            &rT[(min(max(ry, 0), 63) * 64 + min(max(rx, 0), 63)) * 64];
        float4 ra = rp[2 * tx], rb = rp[2 * tx + 1];
        float v = red8(pdot8(T0, T1, ra, rb));
        if (tx == 0 && b < 14) D[w][a * 14 + b] = ok ? v : 0.f;
      }
    }
    __builtin_amdgcn_s_setprio(0);

    // ---- ph4: ref0 bilinear-combine gaussian softmax (wave-local)
    {
      int px = x0 + 2 * w, pix = (y << 6) + px;
      float sc[3];
      float m = -3e38f;
#pragma unroll
      for (int it = 0; it < 3; ++it) {
        unsigned o = lane + (it << 6);
        float scv = -3e38f;
        if (o < 169u) {
          unsigned i = o / 13u, j = o - i * 13u;
          float v = w00 * D[w][i * 14 + j] + w01 * D[w][i * 14 + j + 1] +
                    w10 * D[w][(i + 1) * 14 + j] +
                    w11 * D[w][(i + 1) * 14 + j + 1];
          float di = (float)(((int)i - 6) * ((int)i - 6) +
                             ((int)j - 6) * ((int)j - 6));
          scv = 50.f * __expf(-0.5f * di) * v;
        }
        sc[it] = scv;
        m = fmaxf(m, scv);
      }
      m = wredmax(m);
      float ee[3];
      float s = 0.f, gx = 0.f, gy = 0.f;
#pragma unroll
      for (int it = 0; it < 3; ++it) {
        unsigned o = lane + (it << 6);
        unsigned i = o / 13u, j = o - i * 13u;
        float e = __expf(sc[it] - m);
        ee[it] = e;
        int yy = y + (int)i - 6, xx = px + (int)j - 6;
        bool inb = (o < 169u) && (unsigned)yy < 64u && (unsigned)xx < 64u;
        s += e;
        gx += e * (inb ? (-1.f + (2.f / 63.f) * (float)xx) : 0.f);
        gy += e * (inb ? (-1.f + (2.f / 63.f) * (float)yy) : 0.f);
      }
      s = wredsum(s);
      gx = wredsum(gx);
      gy = wredsum(gy);
      float invS = 1.f / s;
#pragma unroll
      for (int it = 0; it < 3; ++it) {
        unsigned o = lane + (it << 6);
        if (o < 169u) P0[w][o] = ee[it] * invS;
      }
      if (lane == 0) {
        grid[pix * 2 + 0] = gx * invS;
        grid[pix * 2 + 1] = gy * invS;
      }
    }

    // ---- ph5: ref0 inverse-bilinear histogram (wave-local)
    {
#pragma unroll
      for (int it = 0; it < 4; ++it) {
        int idx = lane + (it << 6);  // 14x16-padded
        int a = idx >> 4, b = idx & 15;
        if (a < 14 && b < 14) {
          int ry = iy0 + a, rx = ix0 + b;
          if ((unsigned)ry < 64u && (unsigned)rx < 64u) {
            float wgt = 0.f;
            const float* crp = P0[w];
            if (a < 13) {
              if (b < 13) wgt = fmaf(w00, crp[a * 13 + b], wgt);
              if (b > 0) wgt = fmaf(w01, crp[a * 13 + b - 1], wgt);
            }
            if (a > 0) {
              if (b < 13) wgt = fmaf(w10, crp[(a - 1) * 13 + b], wgt);
              if (b > 0) wgt = fmaf(w11, crp[(a - 1) * 13 + b - 1], wgt);
            }
            if (wgt != 0.f) atomicAdd(&bins[w][lblp[ry * 64 + rx]], wgt);
          }
        }
      }
    }
    __syncthreads();  // bins settled before out write
  } else {
    // ---------------- z = k in {1,2}: plain ref, 4 consecutive pixels -----
    int k = z;
    int x0c = xg * 4;
    opix = -x0c - 1;  // flag consecutive mapping
    const float* rb0 = rT + (k << 18);
    float (*cc2)[169] = (float(*)[169])cc1;
    const float4* tb = (const float4*)&tT[((y << 6) + x0c) << 6];
    float4 t0a = tb[0 * 16 + 2 * tx], t0b = tb[0 * 16 + 2 * tx + 1];
    float4 t1a = tb[1 * 16 + 2 * tx], t1b = tb[1 * 16 + 2 * tx + 1];
    float4 t2a = tb[2 * 16 + 2 * tx], t2b = tb[2 * 16 + 2 * tx + 1];
    float4 t3a = tb[3 * 16 + 2 * tx], t3b = tb[3 * 16 + 2 * tx + 1];

    // ---- ph6: 13x16 union dots -> cc2[px][i*13+j], 7 rounds
    __builtin_amdgcn_s_setprio(1);
    {
#pragma unroll 4
      for (int r = 0; r < 7; ++r) {
        int idx = g + (r << 5);  // 0..223, active < 208
        int i = idx >> 4, u = idx & 15;
        int ry = y + i - 6, rx = x0c - 6 + u;
        bool ok = (i < 13) & ((unsigned)ry < 64u) & ((unsigned)rx < 64u);
        const float4* rp = (const float4*)
            &rb0[min(max(ry, 0), 63) * 4096 + min(max(rx, 0), 63) * 64 +
                 tx * 8];
        float4 ra = rp[0], rb = rp[1];
        float v = red8_4(pdot8(t0a, t0b, ra, rb), pdot8(t1a, t1b, ra, rb),
                         pdot8(t2a, t2b, ra, rb), pdot8(t3a, t3b, ra, rb),
                         tx);
        v = ok ? v : 0.f;
        int j = u - (tx & 3);
        if ((tx < 4) && (i < 13) && ((unsigned)j < 13u))
          cc2[tx & 3][i * 13 + j] = v;
      }
    }
    __builtin_amdgcn_s_setprio(0);
    __syncthreads();  // cc2 complete (covers bins init too)

    // ---- ph7: gaussian softmax + grid + histogram (wave w, pixel w)
    {
      int px = x0c + w, pix = (y << 6) + px;
      float sc[3];
      float m = -3e38f;
#pragma unroll
      for (int it = 0; it < 3; ++it) {
        unsigned o = lane + (it << 6);
        float scv = -3e38f;
        if (o < 169u) {
          unsigned i = o / 13u, j = o - i * 13u;
          float di = (float)(((int)i - 6) * ((int)i - 6) +
                             ((int)j - 6) * ((int)j - 6));
          scv = 50.f * __expf(-0.5f * di) * cc2[w][o];
        }
        sc[it] = scv;
        m = fmaxf(m, scv);
      }
      m = wredmax(m);
      float ee[3];
      float s = 0.f, gx = 0.f, gy = 0.f;
#pragma unroll
      for (int it = 0; it < 3; ++it) {
        unsigned o = lane + (it << 6);
        unsigned i = o / 13u, j = o - i * 13u;
        float e = __expf(sc[it] - m);
        ee[it] = e;
        int yy = y + (int)i - 6, xx = px + (int)j - 6;
        bool inb = (o < 169u) && (unsigned)yy < 64u && (unsigned)xx < 64u;
        s += e;
        gx += e * (inb ? (-1.f + (2.f / 63.f) * (float)xx) : 0.f);
        gy += e * (inb ? (-1.f + (2.f / 63.f) * (float)yy) : 0.f);
      }
      s = wredsum(s);
      gx = wredsum(gx);
      gy = wredsum(gy);
      float invS = 1.f / s;
#pragma unroll
      for (int it = 0; it < 3; ++it) {
        unsigned o = lane + (it << 6);
        if (o < 169u) {
          unsigned i = o / 13u, j = o - i * 13u;
          int yy = y + (int)i - 6, xx = px + (int)j - 6;
          if ((unsigned)yy < 64u && (unsigned)xx < 64u)
            atomicAdd(&bins[w][lblp[(k << 12) + yy * 64 + xx]],
                      ee[it] * invS);
        }
      }
      if (lane == 0) {
        grid[(k * NPIX + pix) * 2 + 0] = gx * invS;
        grid[(k * NPIX + pix) * 2 + 1] = gy * invS;
      }
    }
    __syncthreads();  // bins settled before out write
  }

  // ---- out accumulate: 32 ch x 4 px (out pre-zeroed; 3 adds/elem total)
  if (tid < 128) {
    int pp = tid & 3, c = tid >> 2;
    int px = (opix >= 0) ? (opix + 2 * pp) : (-opix - 1 + pp);
    atomicAdd(&out[c * NPIX + (y << 6) + px], bins[pp][c]);
  }
}

// ---------------------------------------------------------------------------
extern "C" void kernel_launch(void* const* d_in, const int* in_sizes, int n_in,
                              void* d_out, int out_size, void* d_ws,
                              size_t ws_size, hipStream_t stream) {
  const float* fr = (const float*)d_in[0];  // feats_r (3,1,64,64,64)
  const float* ft = (const float*)d_in[1];  // feats_t (1,64,64,64)
  const int* q = (const int*)d_in[2];       // quantized_r (3,1,1,256,256)
  float* out = (float*)d_out;               // 131072 + 24576 floats
  float* grid = out + 32 * NPIX;

  float* ws = (float*)d_ws;
  float* tT = ws;                                        // 4096*64
  float* rT = ws + 262144;                               // 3*4096*64
  unsigned char* lblp = (unsigned char*)(ws + 1048576);  // 3*4096 uchar

  k_transpose<<<dim3(64, 4), 256, 0, stream>>>(ft, fr, q, tT, rT, lblp, out);
  k_fused<<<dim3(16, 64, 3), 256, 0, stream>>>(tT, rT, lblp, out, grid);
}